// Round 2
// baseline (203.289 us; speedup 1.0000x reference)
//
#include <hip/hip_runtime.h>
#include <hip/hip_bf16.h>

typedef __hip_bfloat16 bf16;
typedef __attribute__((ext_vector_type(8))) short short8;
typedef __attribute__((ext_vector_type(4))) float f32x4;

#define BM 128
#define BN 128
#define BK 64

__device__ __forceinline__ void gload_lds16(const void* g, void* l) {
  __builtin_amdgcn_global_load_lds(
      (const __attribute__((address_space(1))) unsigned int*)g,
      (__attribute__((address_space(3))) unsigned int*)l,
      16, 0, 0);
}

// fp32 -> bf16 bulk convert (RNE). n must be a multiple of 2048 (grid-exact).
__global__ __launch_bounds__(256) void f2b(const float* __restrict__ in,
                                           bf16* __restrict__ out, long n) {
  const long i = ((long)blockIdx.x * 256 + threadIdx.x) * 8;
  if (i >= n) return;
  const float4 a = *(const float4*)&in[i];
  const float4 b = *(const float4*)&in[i + 4];
  const float va[8] = {a.x, a.y, a.z, a.w, b.x, b.y, b.z, b.w};
  union { bf16 h; short s; } u;
  short8 o;
#pragma unroll
  for (int j = 0; j < 8; ++j) { u.h = __float2bfloat16(va[j]); o[j] = u.s; }
  *(short8*)&out[i] = o;
}

// MODE: 0 = plain bf16 store
//       1 = transposed store (V^T: out[b][d][s]), batch derived from row block
//       2 = scores: skip blocks with bn > bm (fully causal-masked)
//       3 = PV: causal K-limit  kEnd = (bm+1)*BM
//       4 = plain fp32 store (final projection into d_out)
template <int MODE>
__global__ __launch_bounds__(256, 2) void gemm_bt(
    const bf16* __restrict__ Aall, const bf16* __restrict__ Ball,
    void* __restrict__ Call, int M, int N, int K, long sA, long sB, long sC) {
  const int bm = blockIdx.x, bn = blockIdx.y, bz = blockIdx.z;
  if (MODE == 2 && bn > bm) return;
  const bf16* A = Aall + sA * bz;
  const bf16* B = Ball + sB * bz;
  const int kEnd = (MODE == 3) ? (((bm + 1) * BM < K) ? (bm + 1) * BM : K) : K;

  __shared__ bf16 smem[BM * BK + BN * BK];  // 32 KiB; reused for transpose epilogue
  bf16* As = smem;
  bf16* Bs = smem + BM * BK;

  const int t = threadIdx.x;
  const int lane = t & 63;
  const int wid = t >> 6;
  const int wr = (wid >> 1) * 64;  // wave's 64x64 quadrant
  const int wc = (wid & 1) * 64;
  const int lr = lane & 15;        // A/B fragment row (and C col)
  const int lk = (lane >> 4) * 8;  // fragment k-offset

  f32x4 acc[4][4] = {};

  const int arow = bm * BM;
  const int brow = bn * BN;

  for (int k0 = 0; k0 < kEnd; k0 += BK) {
    // stage A(128x64) and B(128x64) via global_load_lds dwordx4
    // LDS dest byte = p*4096 + wid*1024 + lane*16  -> wave-uniform base + lane*16
#pragma unroll
    for (int p = 0; p < 4; ++p) {
      const int row = p * 32 + (t >> 3);
      const int col = (t & 7) * 8;
      gload_lds16(A + (long)(arow + row) * K + k0 + col, &As[row * BK + col]);
      gload_lds16(B + (long)(brow + row) * K + k0 + col, &Bs[row * BK + col]);
    }
    __syncthreads();
#pragma unroll
    for (int kk = 0; kk < BK; kk += 32) {
      short8 a[4], b[4];
#pragma unroll
      for (int m = 0; m < 4; ++m)
        a[m] = *(const short8*)&As[(wr + m * 16 + lr) * BK + kk + lk];
#pragma unroll
      for (int n = 0; n < 4; ++n)
        b[n] = *(const short8*)&Bs[(wc + n * 16 + lr) * BK + kk + lk];
#pragma unroll
      for (int m = 0; m < 4; ++m)
#pragma unroll
        for (int n = 0; n < 4; ++n)
          acc[m][n] =
              __builtin_amdgcn_mfma_f32_16x16x32_bf16(a[m], b[n], acc[m][n], 0, 0, 0);
    }
    __syncthreads();
  }

  if (MODE == 4) {
    float* C = (float*)Call + sC * bz;
    // C/D layout (m89-verified): col = lane&15, row = (lane>>4)*4 + r
#pragma unroll
    for (int m = 0; m < 4; ++m)
#pragma unroll
      for (int n = 0; n < 4; ++n)
#pragma unroll
        for (int r = 0; r < 4; ++r) {
          const int row = arow + wr + m * 16 + (lane >> 4) * 4 + r;
          const int col = brow + wc + n * 16 + lr;
          C[(long)row * N + col] = acc[m][n][r];
        }
  } else if (MODE != 1) {
    bf16* C = (bf16*)Call + sC * bz;
#pragma unroll
    for (int m = 0; m < 4; ++m)
#pragma unroll
      for (int n = 0; n < 4; ++n)
#pragma unroll
        for (int r = 0; r < 4; ++r) {
          const int row = arow + wr + m * 16 + (lane >> 4) * 4 + r;
          const int col = brow + wc + n * 16 + lr;
          C[(long)row * N + col] = __float2bfloat16(acc[m][n][r]);
        }
  } else {
    // transpose through LDS, then coalesced 16B stores of V^T[b][d][s]
    bf16* C = (bf16*)Call;
    __syncthreads();
    bf16* T = smem;  // [128 d][128 s]
#pragma unroll
    for (int m = 0; m < 4; ++m)
#pragma unroll
      for (int n = 0; n < 4; ++n)
#pragma unroll
        for (int r = 0; r < 4; ++r) {
          const int srow = wr + m * 16 + (lane >> 4) * 4 + r;  // s-local
          const int dcol = wc + n * 16 + lr;                   // d-local
          T[dcol * BM + srow] = __float2bfloat16(acc[m][n][r]);
        }
    __syncthreads();
    const int batch = arow >> 10;  // 1024 rows per batch
    const int s0 = arow & 1023;
    const int d0 = brow;
    const int dl = t >> 1;
#pragma unroll
    for (int i = 0; i < 8; ++i) {
      const int sb = (t & 1) * 64 + i * 8;
      *(float4*)&C[((long)batch * 1024 + d0 + dl) * 1024 + s0 + sb] =
          *(const float4*)&T[dl * BM + sb];
    }
  }
}

// In-place causal softmax over bf16 score rows; writes P (bf16), zeros above diag.
__global__ __launch_bounds__(256) void softmax_causal(bf16* __restrict__ P, int S) {
  const int q = blockIdx.x;
  const int b = blockIdx.y;
  bf16* row = P + ((long)b * S + q) * S;
  const int t = threadIdx.x;
  const int n = q + 1;  // valid causal length
  __shared__ float red[8];

  float v[4];
  float mx = -1e30f;
#pragma unroll
  for (int i = 0; i < 4; ++i) {
    const int k = t + i * 256;
    v[i] = (k < n) ? __bfloat162float(row[k]) * 0.03125f : -1e30f;  // 1/sqrt(1024)
    mx = fmaxf(mx, v[i]);
  }
#pragma unroll
  for (int o = 32; o > 0; o >>= 1) mx = fmaxf(mx, __shfl_xor(mx, o, 64));
  if ((t & 63) == 0) red[t >> 6] = mx;
  __syncthreads();
  mx = fmaxf(fmaxf(red[0], red[1]), fmaxf(red[2], red[3]));

  float e[4];
  float s = 0.f;
#pragma unroll
  for (int i = 0; i < 4; ++i) {
    const int k = t + i * 256;
    e[i] = (k < n) ? __expf(v[i] - mx) : 0.f;
    s += e[i];
  }
#pragma unroll
  for (int o = 32; o > 0; o >>= 1) s += __shfl_xor(s, o, 64);
  if ((t & 63) == 0) red[4 + (t >> 6)] = s;
  __syncthreads();
  s = (red[4] + red[5]) + (red[6] + red[7]);
  const float inv = 1.f / s;
#pragma unroll
  for (int i = 0; i < 4; ++i) {
    const int k = t + i * 256;
    row[k] = __float2bfloat16(e[i] * inv);  // zeros for k >= n
  }
}

extern "C" void kernel_launch(void* const* d_in, const int* in_sizes, int n_in,
                              void* d_out, int out_size, void* d_ws, size_t ws_size,
                              hipStream_t stream) {
  (void)in_sizes; (void)n_in; (void)out_size; (void)ws_size;
  const float* x  = (const float*)d_in[0];
  const float* wq = (const float*)d_in[1];
  const float* wk = (const float*)d_in[2];
  const float* wv = (const float*)d_in[3];
  const float* wo = (const float*)d_in[4];
  float* out = (float*)d_out;
  bf16* ws = (bf16*)d_ws;

  const long SB = 8192L * 1024;  // elements of one [8][1024][1024] buffer
  const long SW = 1024L * 1024;  // one weight matrix
  const long SS = 1024L * 1024;  // per-batch score matrix

  bf16* xb  = ws;                     // [8][1024 s][1024 d]        16.8 MB
  bf16* wqb = ws + SB;                //                             2.1 MB
  bf16* wkb = ws + SB + SW;
  bf16* wvb = ws + SB + 2 * SW;
  bf16* wob = ws + SB + 3 * SW;
  bf16* Q   = ws + SB + 4 * SW;       // [8][1024 s][1024 d]; reused as attn-out
  bf16* Kb  = Q + SB;                 // [8][1024 s][1024 d]
  bf16* VT  = Q + 2 * SB;             // [8][1024 d][1024 s]
  bf16* P   = Q + 3 * SB;             // scores then P in place [8][1024 q][1024 k]
  // total ws: ~92.3 MB

  dim3 blk(256);
  // fp32 -> bf16 conversions
  f2b<<<dim3(4096), blk, 0, stream>>>(x, xb, SB);
  f2b<<<dim3(512), blk, 0, stream>>>(wq, wqb, SW);
  f2b<<<dim3(512), blk, 0, stream>>>(wk, wkb, SW);
  f2b<<<dim3(512), blk, 0, stream>>>(wv, wvb, SW);
  f2b<<<dim3(512), blk, 0, stream>>>(wo, wob, SW);

  // projections: M=8192, N=K=1024
  gemm_bt<0><<<dim3(64, 8, 1), blk, 0, stream>>>(xb, wqb, Q,  8192, 1024, 1024, 0, 0, 0);
  gemm_bt<0><<<dim3(64, 8, 1), blk, 0, stream>>>(xb, wkb, Kb, 8192, 1024, 1024, 0, 0, 0);
  gemm_bt<1><<<dim3(64, 8, 1), blk, 0, stream>>>(xb, wvb, VT, 8192, 1024, 1024, 0, 0, 0);
  // scores = Q K^T (raw, unscaled), lower-triangle blocks only
  gemm_bt<2><<<dim3(8, 8, 8), blk, 0, stream>>>(Q, Kb, P, 1024, 1024, 1024, SS, SS, SS);
  // causal softmax in place (applies 1/32 scale)
  softmax_causal<<<dim3(1024, 8), blk, 0, stream>>>(P, 1024);
  // attn_out = P @ V  (B operand is V^T, causal K-limit); AO reuses Q's buffer
  gemm_bt<3><<<dim3(8, 8, 8), blk, 0, stream>>>(P, VT, Q, 1024, 1024, 1024, SS, SS, SS);
  // output projection -> fp32 d_out
  gemm_bt<4><<<dim3(64, 8, 1), blk, 0, stream>>>(Q, wob, out, 8192, 1024, 1024, 0, 0, 0);
}

// Round 3
// 179.509 us; speedup vs baseline: 1.1325x; 1.1325x over previous
//
#include <hip/hip_runtime.h>
#include <hip/hip_bf16.h>

typedef __hip_bfloat16 bf16;
typedef __attribute__((ext_vector_type(8))) short short8;
typedef __attribute__((ext_vector_type(4))) float f32x4;

#define SBAR() asm volatile("s_barrier" ::: "memory")
#define VMCNT4() asm volatile("s_waitcnt vmcnt(4)" ::: "memory")
#define VMCNT0() asm volatile("s_waitcnt vmcnt(0)" ::: "memory")

__device__ __forceinline__ void gload_lds16(const bf16* g, bf16* l) {
  __builtin_amdgcn_global_load_lds(
      (const __attribute__((address_space(1))) unsigned int*)g,
      (__attribute__((address_space(3))) unsigned int*)l, 16, 0, 0);
}

// Stage one 128x64 half-tile (row-major, ld=1024) into a linear 16KB LDS slot.
// Global source col is XOR-swizzled so that swizzled LDS reads are conflict-free
// (rule 21: linear dest + inverse-swizzled source + swizzled read).
__device__ __forceinline__ void stage_half(const bf16* gbase, bf16* slot, int tid) {
  const int r = tid >> 3;                      // 0..63
  const int c = ((tid & 7) ^ (r & 7)) << 3;    // swizzled 16B chunk
  gload_lds16(gbase + (long)r * 1024 + c, slot + tid * 8);
  gload_lds16(gbase + (long)(r + 64) * 1024 + c, slot + 4096 + tid * 8);
}

// Swizzled fragment read: logical (row, 16B-chunk c16) of a [128][64] half-slot.
__device__ __forceinline__ short8 lds_frag(const bf16* slot, int row, int c16) {
  return *(const short8*)(slot + row * 64 + ((c16 ^ (row & 7)) << 3));
}

// 256x256 tile, BK=64, 8 waves (2Mx4N), 8-phase counted-vmcnt schedule (T2+T3+T4+T5).
// MODE 0: fused QKV projection — bn<4 -> Cq (bf16), bn<8 -> Ck (bf16),
//         bn>=8 -> Cv transposed (V^T[b][d][s], bf16).
// MODE 1: plain fp32 store to Cq (final O projection). K fixed at 1024.
template <int MODE>
__global__ __launch_bounds__(512, 2) void gemm256(
    const bf16* __restrict__ A, const bf16* __restrict__ Bq,
    const bf16* __restrict__ Bk, const bf16* __restrict__ Bv,
    void* __restrict__ Cq, void* __restrict__ Ck, void* __restrict__ Cv) {
  __shared__ bf16 smem[65536];  // 128 KiB: A 4 half-slots + B 4 half-slots
  const int bm = blockIdx.x, bn = blockIdx.y;
  const int tid = threadIdx.x;
  const int lane = tid & 63;
  const int wid = tid >> 6;
  const int wr = wid >> 2;        // 0..1  (M)
  const int wc = wid & 3;         // 0..3  (N)
  const int lr = lane & 15;
  const int c16 = lane >> 4;      // 0..3
  const int g = (MODE == 0) ? (bn >> 2) : 0;
  const int bcol = (MODE == 0) ? (bn & 3) * 256 : bn * 256;
  const bf16* Bsel = (MODE == 0) ? (g == 0 ? Bq : (g == 1 ? Bk : Bv)) : Bq;
  const int arow = bm * 256;
  const bf16* Ag = A + (long)arow * 1024;
  const bf16* Bg = Bsel + (long)bcol * 1024;
  bf16* sA = smem;           // slots: parity*2 + half, 8192 elems each
  bf16* sB = smem + 32768;

  // prologue stage stream: A(0)h0, A(0)h1, B(0)h0, B(0)h1, A(1)h0, A(1)h1
  stage_half(Ag, sA, tid);
  stage_half(Ag + 128 * 1024, sA + 8192, tid);
  stage_half(Bg, sB, tid);
  stage_half(Bg + 128 * 1024, sB + 8192, tid);
  stage_half(Ag + 64, sA + 16384, tid);
  stage_half(Ag + 128 * 1024 + 64, sA + 24576, tid);
  VMCNT4();  // tile 0 landed; A(1) may stay in flight
  SBAR();

  f32x4 acc[8][4] = {};
  const int NT = 16;  // K=1024 / BK=64
  for (int t = 0; t < NT; ++t) {
    const int rp = t & 1;
    const bf16* As = sA + (rp * 2 + wr) * 8192;
    const bf16* Bs = sB + (rp * 2 + (wc >> 1)) * 8192;
    const int brb = (wc & 1) * 64;
    const int sp2 = (rp ^ 1) * 2;
    short8 aq0[4][2], aq1[4][2], bq0[2][2], bq1[2][2];

    // ---- phase 0: read Aq0 + Bq0; stage B(t+1)h0; MFMA (m0-3 x n0-1)
#pragma unroll
    for (int m = 0; m < 4; ++m)
#pragma unroll
      for (int ks = 0; ks < 2; ++ks)
        aq0[m][ks] = lds_frag(As, m * 16 + lr, c16 + ks * 4);
#pragma unroll
    for (int n = 0; n < 2; ++n)
#pragma unroll
      for (int ks = 0; ks < 2; ++ks)
        bq0[n][ks] = lds_frag(Bs, brb + n * 16 + lr, c16 + ks * 4);
    if (t + 1 < NT) stage_half(Bg + (t + 1) * 64, sB + sp2 * 8192, tid);
    SBAR();
    __builtin_amdgcn_s_setprio(1);
#pragma unroll
    for (int m = 0; m < 4; ++m)
#pragma unroll
      for (int n = 0; n < 2; ++n)
#pragma unroll
        for (int ks = 0; ks < 2; ++ks)
          acc[m][n] = __builtin_amdgcn_mfma_f32_16x16x32_bf16(
              aq0[m][ks], bq0[n][ks], acc[m][n], 0, 0, 0);
    __builtin_amdgcn_s_setprio(0);
    SBAR();

    // ---- phase 1: read Bq1; stage B(t+1)h1; MFMA (m0-3 x n2-3)  [aq0 dies]
#pragma unroll
    for (int n = 0; n < 2; ++n)
#pragma unroll
      for (int ks = 0; ks < 2; ++ks)
        bq1[n][ks] = lds_frag(Bs, brb + (n + 2) * 16 + lr, c16 + ks * 4);
    if (t + 1 < NT) stage_half(Bg + 128 * 1024 + (t + 1) * 64, sB + (sp2 + 1) * 8192, tid);
    SBAR();
    __builtin_amdgcn_s_setprio(1);
#pragma unroll
    for (int m = 0; m < 4; ++m)
#pragma unroll
      for (int n = 0; n < 2; ++n)
#pragma unroll
        for (int ks = 0; ks < 2; ++ks)
          acc[m][n + 2] = __builtin_amdgcn_mfma_f32_16x16x32_bf16(
              aq0[m][ks], bq1[n][ks], acc[m][n + 2], 0, 0, 0);
    __builtin_amdgcn_s_setprio(0);
    SBAR();

    // ---- phase 2: read Aq1; MFMA (m4-7 x n2-3)  [bq1 dies; A slot now free]
#pragma unroll
    for (int m = 0; m < 4; ++m)
#pragma unroll
      for (int ks = 0; ks < 2; ++ks)
        aq1[m][ks] = lds_frag(As, (m + 4) * 16 + lr, c16 + ks * 4);
    SBAR();
    __builtin_amdgcn_s_setprio(1);
#pragma unroll
    for (int m = 0; m < 4; ++m)
#pragma unroll
      for (int n = 0; n < 2; ++n)
#pragma unroll
        for (int ks = 0; ks < 2; ++ks)
          acc[m + 4][n + 2] = __builtin_amdgcn_mfma_f32_16x16x32_bf16(
              aq1[m][ks], bq1[n][ks], acc[m + 4][n + 2], 0, 0, 0);
    __builtin_amdgcn_s_setprio(0);
    SBAR();

    // ---- phase 3: stage A(t+2) both halves; counted vmcnt; MFMA (m4-7 x n0-1)
    if (t + 2 < NT) {
      stage_half(Ag + (t + 2) * 64, sA + rp * 2 * 8192, tid);
      stage_half(Ag + 128 * 1024 + (t + 2) * 64, sA + (rp * 2 + 1) * 8192, tid);
      VMCNT4();  // allow only the 4 A(t+2) loads in flight -> tile t+1 landed
    } else if (t + 1 < NT) {
      VMCNT0();  // tail: drain B(NT-1)
    }
    SBAR();
    __builtin_amdgcn_s_setprio(1);
#pragma unroll
    for (int m = 0; m < 4; ++m)
#pragma unroll
      for (int n = 0; n < 2; ++n)
#pragma unroll
        for (int ks = 0; ks < 2; ++ks)
          acc[m + 4][n] = __builtin_amdgcn_mfma_f32_16x16x32_bf16(
              aq1[m][ks], bq0[n][ks], acc[m + 4][n], 0, 0, 0);
    __builtin_amdgcn_s_setprio(0);
    SBAR();
  }

  // ---- epilogue. C/D layout (m89): col = lane&15, row = (lane>>4)*4 + r
  const int r0 = (lane >> 4) * 4;
  if (MODE == 1) {
    float* C = (float*)Cq;
#pragma unroll
    for (int m = 0; m < 8; ++m)
#pragma unroll
      for (int n = 0; n < 4; ++n)
#pragma unroll
        for (int r = 0; r < 4; ++r)
          C[(long)(arow + wr * 128 + m * 16 + r0 + r) * 1024 + bcol + wc * 64 + n * 16 + lr] =
              acc[m][n][r];
  } else if (g < 2) {
    bf16* C = (bf16*)(g == 0 ? Cq : Ck);
#pragma unroll
    for (int m = 0; m < 8; ++m)
#pragma unroll
      for (int n = 0; n < 4; ++n)
#pragma unroll
        for (int r = 0; r < 4; ++r)
          C[(long)(arow + wr * 128 + m * 16 + r0 + r) * 1024 + bcol + wc * 64 + n * 16 + lr] =
              __float2bfloat16(acc[m][n][r]);
  } else {
    // V: transpose through (swizzled) LDS, store V^T[b][d][s] coalesced.
    char* T = (char*)smem;  // loop's final barrier + vmcnt(0) drain make smem free
#pragma unroll
    for (int m = 0; m < 8; ++m)
#pragma unroll
      for (int n = 0; n < 4; ++n)
#pragma unroll
        for (int r = 0; r < 4; ++r) {
          const int srow = wr * 128 + m * 16 + r0 + r;   // s-local
          const int dcol = wc * 64 + n * 16 + lr;        // d-local
          *(bf16*)(T + dcol * 512 + ((srow * 2) ^ ((dcol & 7) << 4))) =
              __float2bfloat16(acc[m][n][r]);
        }
    __syncthreads();
    const int d = tid >> 1;
    const long rowbase = ((long)(arow >> 10) * 1024 + bcol + d) * 1024 + (arow & 1023);
    bf16* C = (bf16*)Cv;
#pragma unroll
    for (int i = 0; i < 16; ++i) {
      const int s = (tid & 1) * 128 + i * 8;
      const float4 v = *(const float4*)(T + d * 512 + ((s * 2) ^ ((d & 7) << 4)));
      *(float4*)&C[rowbase + s] = v;
    }
  }
}

// ---------------- 128x128 m97-structure GEMM for the per-batch attention GEMMs
#define BM 128
#define BK 64

// MODE 2 = scores: skip blocks with bn > bm; MODE 3 = PV: causal K-limit
template <int MODE>
__global__ __launch_bounds__(256, 2) void gemm_bt(
    const bf16* __restrict__ Aall, const bf16* __restrict__ Ball,
    bf16* __restrict__ Call, int N, int K, long sAB) {
  const int bm = blockIdx.x, bn = blockIdx.y, bz = blockIdx.z;
  if (MODE == 2 && bn > bm) return;
  const bf16* A = Aall + sAB * bz;
  const bf16* B = Ball + sAB * bz;
  bf16* C = Call + sAB * bz;
  const int kEnd = (MODE == 3) ? (((bm + 1) * BM < K) ? (bm + 1) * BM : K) : K;

  __shared__ bf16 smem[BM * BK * 2];
  bf16* As = smem;
  bf16* Bs = smem + BM * BK;
  const int t = threadIdx.x;
  const int lane = t & 63;
  const int wid = t >> 6;
  const int wr = (wid >> 1) * 64;
  const int wc = (wid & 1) * 64;
  const int lr = lane & 15;
  const int lk = (lane >> 4) * 8;
  f32x4 acc[4][4] = {};
  const int arow = bm * BM;
  const int brow = bn * BM;

  for (int k0 = 0; k0 < kEnd; k0 += BK) {
#pragma unroll
    for (int p = 0; p < 4; ++p) {
      const int row = p * 32 + (t >> 3);
      const int col = (t & 7) * 8;
      gload_lds16(A + (long)(arow + row) * K + k0 + col, &As[row * BK + col]);
      gload_lds16(B + (long)(brow + row) * K + k0 + col, &Bs[row * BK + col]);
    }
    __syncthreads();
#pragma unroll
    for (int kk = 0; kk < BK; kk += 32) {
      short8 a[4], b[4];
#pragma unroll
      for (int m = 0; m < 4; ++m)
        a[m] = *(const short8*)&As[(wr + m * 16 + lr) * BK + kk + lk];
#pragma unroll
      for (int n = 0; n < 4; ++n)
        b[n] = *(const short8*)&Bs[(wc + n * 16 + lr) * BK + kk + lk];
#pragma unroll
      for (int m = 0; m < 4; ++m)
#pragma unroll
        for (int n = 0; n < 4; ++n)
          acc[m][n] =
              __builtin_amdgcn_mfma_f32_16x16x32_bf16(a[m], b[n], acc[m][n], 0, 0, 0);
    }
    __syncthreads();
  }
#pragma unroll
  for (int m = 0; m < 4; ++m)
#pragma unroll
    for (int n = 0; n < 4; ++n)
#pragma unroll
      for (int r = 0; r < 4; ++r) {
        const int row = arow + wr + m * 16 + (lane >> 4) * 4 + r;
        const int col = brow + wc + n * 16 + lr;
        C[(long)row * N + col] = __float2bfloat16(acc[m][n][r]);
      }
}

// fp32 -> bf16 bulk convert, all 5 inputs in one launch.
__global__ __launch_bounds__(256) void f2b_all(
    const float* __restrict__ x, const float* __restrict__ wq,
    const float* __restrict__ wk, const float* __restrict__ wv,
    const float* __restrict__ wo, bf16* __restrict__ xb, bf16* __restrict__ wqb,
    bf16* __restrict__ wkb, bf16* __restrict__ wvb, bf16* __restrict__ wob) {
  const int bid = blockIdx.x;
  const float* src;
  bf16* dst;
  long base;
  if (bid < 4096) {
    src = x; dst = xb; base = (long)bid * 2048;
  } else {
    const int w = (bid - 4096) >> 9;
    base = (long)((bid - 4096) & 511) * 2048;
    src = (w == 0) ? wq : (w == 1) ? wk : (w == 2) ? wv : wo;
    dst = (w == 0) ? wqb : (w == 1) ? wkb : (w == 2) ? wvb : wob;
  }
  const long i = base + threadIdx.x * 8;
  const float4 a = *(const float4*)&src[i];
  const float4 b = *(const float4*)&src[i + 4];
  const float va[8] = {a.x, a.y, a.z, a.w, b.x, b.y, b.z, b.w};
  union { bf16 h; short s; } u;
  short8 o;
#pragma unroll
  for (int j = 0; j < 8; ++j) { u.h = __float2bfloat16(va[j]); o[j] = u.s; }
  *(short8*)&dst[i] = o;
}

// In-place causal softmax over bf16 score rows (applies 1/32 scale).
__global__ __launch_bounds__(256) void softmax_causal(bf16* __restrict__ P, int S) {
  const int q = blockIdx.x;
  const int b = blockIdx.y;
  bf16* row = P + ((long)b * S + q) * S;
  const int t = threadIdx.x;
  const int n = q + 1;
  __shared__ float red[8];
  float v[4];
  float mx = -1e30f;
#pragma unroll
  for (int i = 0; i < 4; ++i) {
    const int k = t + i * 256;
    v[i] = (k < n) ? __bfloat162float(row[k]) * 0.03125f : -1e30f;
    mx = fmaxf(mx, v[i]);
  }
#pragma unroll
  for (int o = 32; o > 0; o >>= 1) mx = fmaxf(mx, __shfl_xor(mx, o, 64));
  if ((t & 63) == 0) red[t >> 6] = mx;
  __syncthreads();
  mx = fmaxf(fmaxf(red[0], red[1]), fmaxf(red[2], red[3]));
  float e[4];
  float s = 0.f;
#pragma unroll
  for (int i = 0; i < 4; ++i) {
    const int k = t + i * 256;
    e[i] = (k < n) ? __expf(v[i] - mx) : 0.f;
    s += e[i];
  }
#pragma unroll
  for (int o = 32; o > 0; o >>= 1) s += __shfl_xor(s, o, 64);
  if ((t & 63) == 0) red[4 + (t >> 6)] = s;
  __syncthreads();
  s = (red[4] + red[5]) + (red[6] + red[7]);
  const float inv = 1.f / s;
#pragma unroll
  for (int i = 0; i < 4; ++i) {
    const int k = t + i * 256;
    row[k] = __float2bfloat16(e[i] * inv);
  }
}

extern "C" void kernel_launch(void* const* d_in, const int* in_sizes, int n_in,
                              void* d_out, int out_size, void* d_ws, size_t ws_size,
                              hipStream_t stream) {
  (void)in_sizes; (void)n_in; (void)out_size; (void)ws_size;
  const float* x  = (const float*)d_in[0];
  const float* wq = (const float*)d_in[1];
  const float* wk = (const float*)d_in[2];
  const float* wv = (const float*)d_in[3];
  const float* wo = (const float*)d_in[4];
  float* out = (float*)d_out;
  bf16* ws = (bf16*)d_ws;

  const long SB = 8192L * 1024;
  const long SW = 1024L * 1024;
  const long SS = 1024L * 1024;

  bf16* xb  = ws;
  bf16* wqb = ws + SB;
  bf16* wkb = ws + SB + SW;
  bf16* wvb = ws + SB + 2 * SW;
  bf16* wob = ws + SB + 3 * SW;
  bf16* Q   = ws + SB + 4 * SW;   // [8][s][d]; reused as attn-out
  bf16* Kb  = Q + SB;             // [8][s][d]
  bf16* VT  = Q + 2 * SB;         // [8][d][s]
  bf16* P   = Q + 3 * SB;         // scores / P in place

  f2b_all<<<dim3(6144), dim3(256), 0, stream>>>(x, wq, wk, wv, wo, xb, wqb, wkb, wvb, wob);
  // fused Q/K/V projections (V stored transposed)
  gemm256<0><<<dim3(32, 12), dim3(512), 0, stream>>>(xb, wqb, wkb, wvb, Q, Kb, VT);
  // scores = Q K^T, lower-triangle blocks only
  gemm_bt<2><<<dim3(8, 8, 8), dim3(256), 0, stream>>>(Q, Kb, P, 1024, 1024, SS);
  softmax_causal<<<dim3(1024, 8), dim3(256), 0, stream>>>(P, 1024);
  // attn_out = P @ V (B operand = V^T, causal K-limit); into Q's buffer
  gemm_bt<3><<<dim3(8, 8, 8), dim3(256), 0, stream>>>(P, VT, Q, 1024, 1024, SS);
  // output projection -> fp32 d_out
  gemm256<1><<<dim3(32, 4), dim3(512), 0, stream>>>(Q, wob, nullptr, nullptr, out, nullptr, nullptr);
}